// Round 1
// baseline (273.401 us; speedup 1.0000x reference)
//
#include <hip/hip_runtime.h>
#include <cstdint>
#include <cstddef>

#define NEXPERT 32
#define KIN 256
#define NOUT 256
#define NTOK 524288
#define BM 64

typedef float f32x4 __attribute__((ext_vector_type(4)));
typedef __bf16 bf16x8 __attribute__((ext_vector_type(8)));
typedef unsigned short u16;
typedef u16 u16x8 __attribute__((ext_vector_type(8)));

union BF8 { u16x8 u; bf16x8 b; };

__device__ __forceinline__ u16 f2bf(float f) {
  unsigned u = __float_as_uint(f);
  return (u16)((u + 0x7FFFu + ((u >> 16) & 1u)) >> 16);  // RNE
}

// ---- pre-kernel: W fp32 -> bf16 into workspace (exact grid, no bounds) ----
__global__ void conv_w_kernel(const float* __restrict__ w, u16* __restrict__ wb) {
  const int i = (blockIdx.x * 256 + threadIdx.x) * 4;
  const float4 v = *reinterpret_cast<const float4*>(w + i);
  ushort4 o;
  o.x = f2bf(v.x); o.y = f2bf(v.y); o.z = f2bf(v.z); o.w = f2bf(v.w);
  *reinterpret_cast<ushort4*>(wb + i) = o;
}

// ---- grouped GEMM: out[t] = inp[t] @ W[eid(t)]^T ----
// block = 256 threads = 4 waves; tile BM=64 x BN=256; BK=64, 4 K-steps.
// wave w owns output cols [w*64, w*64+64). per-wave acc: 4x4 frags of 16x16.
template<bool WSBF>
__global__ __launch_bounds__(256, 3)
void moe_gemm_kernel(const float* __restrict__ inp,
                     const float* __restrict__ w32,
                     const u16* __restrict__ wbf,
                     const int* __restrict__ counts,
                     float* __restrict__ out)
{
  __shared__ u16 sA[BM * 64];        // 8 KB, XOR-swizzled rows of 128 B
  __shared__ int sCum[NEXPERT + 1];

  const int tid  = threadIdx.x;
  const int lane = tid & 63;
  const int wv   = tid >> 6;   // 0..3 -> column block
  const int l15  = lane & 15;
  const int lg   = lane >> 4;  // 0..3

  if (tid == 0) {
    // dtype probe: counts may be int32 (expected) or int64
    const long long* c64 = reinterpret_cast<const long long*>(counts);
    const long long probe = c64[0];
    const bool is64 = (probe >= 0 && probe < (1ll << 31));
    int c = 0;
    sCum[0] = 0;
    for (int i2 = 0; i2 < NEXPERT; ++i2) {
      const int ci = is64 ? (int)c64[i2] : counts[i2];
      c += ci;
      sCum[i2 + 1] = c;
    }
  }
  __syncthreads();

  const int t0 = blockIdx.x * BM;
  const int t1 = t0 + BM;

  int ee = 0;
  while (sCum[ee + 1] <= t0) ++ee;   // first expert covering t0

  int rb = t0;
  while (rb < t1) {
    const int re = min(t1, sCum[ee + 1]);
    if (re > rb) {
      const int e = ee;
      f32x4 acc[4][4];
      const f32x4 zero = {0.f, 0.f, 0.f, 0.f};
#pragma unroll
      for (int m = 0; m < 4; ++m)
#pragma unroll
        for (int n = 0; n < 4; ++n)
          acc[m][n] = zero;

      for (int ks = 0; ks < 4; ++ks) {
        const int k0 = ks * 64;
        __syncthreads();   // previous tile's LDS reads done
        // ---- stage A tile [64 rows x 64 k] fp32 -> bf16 LDS (swizzled) ----
        {
          const int srow = tid >> 2;            // 0..63
          const int cst  = (tid & 3) << 4;      // 0,16,32,48 (elems)
          const float4* sp4 =
              reinterpret_cast<const float4*>(inp + (size_t)(t0 + srow) * KIN + (k0 + cst));
          const float4 v0 = sp4[0], v1 = sp4[1], v2 = sp4[2], v3 = sp4[3];
          u16x8 h0, h1;
          h0[0]=f2bf(v0.x); h0[1]=f2bf(v0.y); h0[2]=f2bf(v0.z); h0[3]=f2bf(v0.w);
          h0[4]=f2bf(v1.x); h0[5]=f2bf(v1.y); h0[6]=f2bf(v1.z); h0[7]=f2bf(v1.w);
          h1[0]=f2bf(v2.x); h1[1]=f2bf(v2.y); h1[2]=f2bf(v2.z); h1[3]=f2bf(v2.w);
          h1[4]=f2bf(v3.x); h1[5]=f2bf(v3.y); h1[6]=f2bf(v3.z); h1[7]=f2bf(v3.w);
          const int rx = (srow & 7) << 4;
          char* rbase = reinterpret_cast<char*>(sA) + srow * 128;
          const int cb = cst << 1;              // byte offset in row
          *reinterpret_cast<u16x8*>(rbase + ((cb     ) ^ rx)) = h0;
          *reinterpret_cast<u16x8*>(rbase + ((cb + 16) ^ rx)) = h1;
        }
        // ---- B fragments direct from global (bf16 ws, or fp32 fallback) ----
        BF8 bfr[4][2];
        if (WSBF) {
          const u16* wb = wbf + ((size_t)e << 16);
#pragma unroll
          for (int n = 0; n < 4; ++n) {
            const int rown = (wv << 6) + (n << 4) + l15;
#pragma unroll
            for (int kk = 0; kk < 2; ++kk)
              bfr[n][kk].u = *reinterpret_cast<const u16x8*>(
                  wb + (size_t)rown * KIN + k0 + kk * 32 + lg * 8);
          }
        } else {
          const float* wf = w32 + ((size_t)e << 16);
#pragma unroll
          for (int n = 0; n < 4; ++n) {
            const int rown = (wv << 6) + (n << 4) + l15;
#pragma unroll
            for (int kk = 0; kk < 2; ++kk) {
              const float4* p = reinterpret_cast<const float4*>(
                  wf + (size_t)rown * KIN + k0 + kk * 32 + lg * 8);
              const float4 a0 = p[0], a1 = p[1];
              u16x8 h;
              h[0]=f2bf(a0.x); h[1]=f2bf(a0.y); h[2]=f2bf(a0.z); h[3]=f2bf(a0.w);
              h[4]=f2bf(a1.x); h[5]=f2bf(a1.y); h[6]=f2bf(a1.z); h[7]=f2bf(a1.w);
              bfr[n][kk].u = h;
            }
          }
        }
        __syncthreads();   // A tile staged
        // ---- A fragments from LDS + MFMA ----
#pragma unroll
        for (int kk = 0; kk < 2; ++kk) {
          BF8 afr[4];
#pragma unroll
          for (int m = 0; m < 4; ++m) {
            const int row = (m << 4) + l15;
            const int kb  = kk * 64 + (lg << 4);   // byte offset in row
            afr[m].u = *reinterpret_cast<const u16x8*>(
                reinterpret_cast<const char*>(sA) + row * 128 + (kb ^ ((row & 7) << 4)));
          }
#pragma unroll
          for (int m = 0; m < 4; ++m)
#pragma unroll
            for (int n = 0; n < 4; ++n)
              acc[m][n] = __builtin_amdgcn_mfma_f32_16x16x32_bf16(
                  afr[m].b, bfr[n][kk].b, acc[m][n], 0, 0, 0);
        }
      }
      // ---- epilogue: masked store (C/D map: col=l15, row=lg*4+j) ----
#pragma unroll
      for (int m = 0; m < 4; ++m) {
        const int rbase = t0 + (m << 4) + (lg << 2);
#pragma unroll
        for (int n = 0; n < 4; ++n) {
          float* op = out + (size_t)rbase * NOUT + (wv << 6) + (n << 4) + l15;
#pragma unroll
          for (int j = 0; j < 4; ++j) {
            const int rg = rbase + j;
            if (rg >= rb && rg < re)
              op[(size_t)j * NOUT] = acc[m][n][j];
          }
        }
      }
    }
    rb = re > rb ? re : rb;   // advance (empty experts: re==rb)
    ++ee;
  }
}

extern "C" void kernel_launch(void* const* d_in, const int* in_sizes, int n_in,
                              void* d_out, int out_size, void* d_ws, size_t ws_size,
                              hipStream_t stream) {
  const float* inp    = (const float*)d_in[0];
  const float* w      = (const float*)d_in[1];
  const int*   counts = (const int*)d_in[2];
  float*       out    = (float*)d_out;

  const size_t wbytes = (size_t)NEXPERT * NOUT * KIN * 2;  // 4 MB bf16 W
  const bool usews = (ws_size >= wbytes);

  if (usews) {
    u16* wbf = (u16*)d_ws;
    const int total = NEXPERT * NOUT * KIN;            // 2,097,152
    conv_w_kernel<<<total / (256 * 4), 256, 0, stream>>>(w, wbf);
    moe_gemm_kernel<true><<<NTOK / BM, 256, 0, stream>>>(inp, w, wbf, counts, out);
  } else {
    moe_gemm_kernel<false><<<NTOK / BM, 256, 0, stream>>>(inp, w, nullptr, counts, out);
  }
}

// Round 3
// 272.653 us; speedup vs baseline: 1.0027x; 1.0027x over previous
//
#include <hip/hip_runtime.h>
#include <cstdint>
#include <cstddef>

#define NEXPERT 32
#define KIN 256
#define NOUT 256
#define NTOK 524288
#define BM 64

typedef float f32x4 __attribute__((ext_vector_type(4)));
typedef __bf16 bf16x8 __attribute__((ext_vector_type(8)));
typedef unsigned short u16;
typedef u16 u16x8 __attribute__((ext_vector_type(8)));

union BF8 { u16x8 u; bf16x8 b; };

__device__ __forceinline__ u16 f2bf(float f) {
  unsigned u = __float_as_uint(f);
  return (u16)((u + 0x7FFFu + ((u >> 16) & 1u)) >> 16);  // RNE
}

// ---- pre-kernel: W fp32 -> bf16 into workspace ----
__global__ void conv_w_kernel(const float* __restrict__ w, u16* __restrict__ wb) {
  const int i = (blockIdx.x * 256 + threadIdx.x) * 4;
  const float4 v = *reinterpret_cast<const float4*>(w + i);
  ushort4 o;
  o.x = f2bf(v.x); o.y = f2bf(v.y); o.z = f2bf(v.z); o.w = f2bf(v.w);
  *reinterpret_cast<ushort4*>(wb + i) = o;
}

// ---- helpers (inline fns, not macros: avoids pp token-pasting pitfalls) ----
__device__ __forceinline__ void gload(const float4* ap4, int ks, float4 (&v)[4]) {
#pragma unroll
  for (int i = 0; i < 4; ++i) v[i] = ap4[ks * 16 + i];
}

__device__ __forceinline__ void cvtw(const float4 (&v)[4], char* rbase, int cb, int rx) {
  u16x8 h0, h1;
  h0[0]=f2bf(v[0].x); h0[1]=f2bf(v[0].y); h0[2]=f2bf(v[0].z); h0[3]=f2bf(v[0].w);
  h0[4]=f2bf(v[1].x); h0[5]=f2bf(v[1].y); h0[6]=f2bf(v[1].z); h0[7]=f2bf(v[1].w);
  h1[0]=f2bf(v[2].x); h1[1]=f2bf(v[2].y); h1[2]=f2bf(v[2].z); h1[3]=f2bf(v[2].w);
  h1[4]=f2bf(v[3].x); h1[5]=f2bf(v[3].y); h1[6]=f2bf(v[3].z); h1[7]=f2bf(v[3].w);
  *reinterpret_cast<u16x8*>(rbase + ((cb     ) ^ rx)) = h0;
  *reinterpret_cast<u16x8*>(rbase + ((cb + 16) ^ rx)) = h1;
}

template<bool WSBF>
__device__ __forceinline__ void ldb(const u16* wB, const float* wF, int ks, BF8 (&dst)[4][2]) {
  if (WSBF) {
#pragma unroll
    for (int n = 0; n < 4; ++n)
#pragma unroll
      for (int kk = 0; kk < 2; ++kk)
        dst[n][kk].u = *reinterpret_cast<const u16x8*>(wB + n * (16 * KIN) + ks * 64 + kk * 32);
  } else {
#pragma unroll
    for (int n = 0; n < 4; ++n)
#pragma unroll
      for (int kk = 0; kk < 2; ++kk) {
        const float4* p = reinterpret_cast<const float4*>(wF + n * (16 * KIN) + ks * 64 + kk * 32);
        const float4 x = p[0], y = p[1];
        u16x8 h;
        h[0]=f2bf(x.x); h[1]=f2bf(x.y); h[2]=f2bf(x.z); h[3]=f2bf(x.w);
        h[4]=f2bf(y.x); h[5]=f2bf(y.y); h[6]=f2bf(y.z); h[7]=f2bf(y.w);
        dst[n][kk].u = h;
      }
  }
}

__device__ __forceinline__ void compute(const char* abase, int lg, int arx,
                                        const BF8 (&bfr)[4][2], f32x4 (&acc)[4][4]) {
#pragma unroll
  for (int kk = 0; kk < 2; ++kk) {
    BF8 af[4];
#pragma unroll
    for (int m = 0; m < 4; ++m)
      af[m].u = *reinterpret_cast<const u16x8*>(
          abase + m * 2048 + ((kk * 64 + (lg << 4)) ^ arx));
#pragma unroll
    for (int m = 0; m < 4; ++m)
#pragma unroll
      for (int n = 0; n < 4; ++n)
        acc[m][n] = __builtin_amdgcn_mfma_f32_16x16x32_bf16(
            af[m].b, bfr[n][kk].b, acc[m][n], 0, 0, 0);
  }
}

// ---- pipelined grouped GEMM ----
// block=256 (4 waves), tile BM=64 x BN=256, BK=64 x 4 steps.
// Double-buffered LDS A (swizzled) + double-buffered B frags; A HBM loads
// issued 2 steps ahead, B L2 loads 1 step ahead; 1 barrier per K-step.
template<bool WSBF>
__global__ __launch_bounds__(256)
void moe_gemm_kernel(const float* __restrict__ inp,
                     const float* __restrict__ w32,
                     const u16* __restrict__ wbf,
                     const int* __restrict__ counts,
                     float* __restrict__ out)
{
  __shared__ u16 sA0[BM * 64];       // 8 KB, XOR-swizzled 128 B rows
  __shared__ u16 sA1[BM * 64];       // 8 KB
  __shared__ int sCum[NEXPERT + 1];

  const int tid  = threadIdx.x;
  const int lane = tid & 63;
  const int wv   = tid >> 6;
  const int l15  = lane & 15;
  const int lg   = lane >> 4;

  // ---- parallel cumsum of counts (lanes 0..31 of wave 0) ----
  if (tid < 32) {
    const long long* c64 = reinterpret_cast<const long long*>(counts);
    const long long p0 = c64[0];
    const bool is64 = (p0 >= 0 && p0 < (1ll << 31));
    int c = is64 ? (int)c64[tid] : counts[tid];
#pragma unroll
    for (int d = 1; d < 32; d <<= 1) {
      int o = __shfl_up(c, d, 64);
      if (tid >= d) c += o;
    }
    sCum[tid + 1] = c;
    if (tid == 0) sCum[0] = 0;
  }
  __syncthreads();

  const int t0 = blockIdx.x * BM;
  const int t1 = t0 + BM;

  // ---- first expert covering t0 via ballot-popcount ----
  int ee;
  {
    const int v = (lane < NEXPERT) ? sCum[lane + 1] : 0x7fffffff;
    const unsigned long long m = __ballot(v <= t0);
    ee = __popcll(m);
  }

  // ---- staging / fragment geometry ----
  const int srow = tid >> 2;                 // 0..63
  const int scol = (tid & 3) << 4;           // 0,16,32,48 elems
  const float4* ap4 =
      reinterpret_cast<const float4*>(inp + (size_t)(t0 + srow) * KIN + scol);
  char* const r0 = reinterpret_cast<char*>(sA0) + srow * 128;
  char* const r1 = reinterpret_cast<char*>(sA1) + srow * 128;
  const int rx = (srow & 7) << 4;
  const int cb = scol << 1;                  // byte offset in row
  const int arx = (l15 & 7) << 4;            // frag-read swizzle
  const char* const a0 = reinterpret_cast<const char*>(sA0) + l15 * 128;
  const char* const a1 = reinterpret_cast<const char*>(sA1) + l15 * 128;

  int rb = t0;
  int e = ee;
  while (rb < t1) {
    const int re = min(t1, sCum[e + 1]);
    if (re > rb) {
      const size_t wro = ((size_t)e << 16) + (size_t)((wv << 6) + l15) * KIN + lg * 8;
      const u16*   wB  = wbf + wro;
      const float* wF  = w32 + wro;

      f32x4 acc[4][4];
      const f32x4 zero = {0.f, 0.f, 0.f, 0.f};
#pragma unroll
      for (int m = 0; m < 4; ++m)
#pragma unroll
        for (int n = 0; n < 4; ++n) acc[m][n] = zero;

      float4 va[4], vb[4];
      BF8 bA[4][2], bB[4][2];

      // prologue: issue HBM A(ks0,ks1) + L2 B(ks0) before any barrier
      gload(ap4, 0, va);
      gload(ap4, 1, vb);
      ldb<WSBF>(wB, wF, 0, bA);
      __syncthreads();            // prior-run LDS readers done
      cvtw(va, r0, cb, rx);
      __syncthreads();            // buf0 visible

      // step 0: compute buf0/bA; prefetch B1, write buf1, load A2
      ldb<WSBF>(wB, wF, 1, bB); cvtw(vb, r1, cb, rx); gload(ap4, 2, va);
      compute(a0, lg, arx, bA, acc);
      __syncthreads();
      // step 1: compute buf1/bB; prefetch B2, write buf0, load A3
      ldb<WSBF>(wB, wF, 2, bA); cvtw(va, r0, cb, rx); gload(ap4, 3, vb);
      compute(a1, lg, arx, bB, acc);
      __syncthreads();
      // step 2: compute buf0/bA; prefetch B3, write buf1
      ldb<WSBF>(wB, wF, 3, bB); cvtw(vb, r1, cb, rx);
      compute(a0, lg, arx, bA, acc);
      __syncthreads();
      // step 3: compute buf1/bB
      compute(a1, lg, arx, bB, acc);

      // ---- epilogue (C/D map: col=l15, row=lg*4+j) ----
      const bool full = (rb == t0) & (re == t1);
      if (full) {
#pragma unroll
        for (int m = 0; m < 4; ++m) {
          const int rbase = t0 + (m << 4) + (lg << 2);
#pragma unroll
          for (int n = 0; n < 4; ++n) {
            float* op = out + (size_t)rbase * NOUT + (wv << 6) + (n << 4) + l15;
#pragma unroll
            for (int j = 0; j < 4; ++j) op[(size_t)j * NOUT] = acc[m][n][j];
          }
        }
      } else {
#pragma unroll
        for (int m = 0; m < 4; ++m) {
          const int rbase = t0 + (m << 4) + (lg << 2);
#pragma unroll
          for (int n = 0; n < 4; ++n) {
            float* op = out + (size_t)rbase * NOUT + (wv << 6) + (n << 4) + l15;
#pragma unroll
            for (int j = 0; j < 4; ++j) {
              const int rg = rbase + j;
              if (rg >= rb && rg < re) op[(size_t)j * NOUT] = acc[m][n][j];
            }
          }
        }
      }
    }
    rb = re > rb ? re : rb;
    ++e;
  }
}

extern "C" void kernel_launch(void* const* d_in, const int* in_sizes, int n_in,
                              void* d_out, int out_size, void* d_ws, size_t ws_size,
                              hipStream_t stream) {
  const float* inp    = (const float*)d_in[0];
  const float* w      = (const float*)d_in[1];
  const int*   counts = (const int*)d_in[2];
  float*       out    = (float*)d_out;

  const size_t wbytes = (size_t)NEXPERT * NOUT * KIN * 2;  // 4 MB bf16 W
  const bool usews = (ws_size >= wbytes);

  if (usews) {
    u16* wbf = (u16*)d_ws;
    const int total = NEXPERT * NOUT * KIN;  // 2,097,152
    conv_w_kernel<<<total / (256 * 4), 256, 0, stream>>>(w, wbf);
    moe_gemm_kernel<true><<<NTOK / BM, 256, 0, stream>>>(inp, w, wbf, counts, out);
  } else {
    moe_gemm_kernel<false><<<NTOK / BM, 256, 0, stream>>>(inp, w, nullptr, counts, out);
  }
}